// Round 10
// baseline (208.694 us; speedup 1.0000x reference)
//
#include <hip/hip_runtime.h>
#include <math.h>

#define NN 50000
#define NE 800000
#define NR 16
#define BNODE 64                          // nodes per dst bucket
#define NBC 782                           // ceil(50000/64) buckets
#define ABLK 256                          // chunks in count/scatter passes
#define CHUNK ((NE + ABLK - 1) / ABLK)    // 3125
#define NTILE (NE / 16)                   // 50000 exact, no tail
#define TPW 4                             // tiles per wave (50000/4/4 = 3125 blocks exact)

typedef __attribute__((ext_vector_type(8))) short short8;
typedef __attribute__((ext_vector_type(4))) float floatx4;

__device__ __forceinline__ unsigned short f2bf(float x) {
    unsigned int u = __float_as_uint(x);
    u += 0x7fffu + ((u >> 16) & 1u);
    return (unsigned short)(u >> 16);
}
__device__ __forceinline__ float bf2f(unsigned short s) {
    return __uint_as_float(((unsigned int)s) << 16);
}

// 16-lane (DPP-row) sum: every lane of each 16-lane row ends with the row total.
// row_ror:N = 0x120|N. Replaces 4x shfl_xor (ds_bpermute) with pure VALU.
__device__ __forceinline__ float rsum16(float x) {
    int t;
    t = __builtin_amdgcn_update_dpp(0, __float_as_int(x), 0x128, 0xF, 0xF, true);
    x += __int_as_float(t);
    t = __builtin_amdgcn_update_dpp(0, __float_as_int(x), 0x124, 0xF, 0xF, true);
    x += __int_as_float(t);
    t = __builtin_amdgcn_update_dpp(0, __float_as_int(x), 0x122, 0xF, 0xF, true);
    x += __int_as_float(t);
    t = __builtin_amdgcn_update_dpp(0, __float_as_int(x), 0x121, 0xF, 0xF, true);
    x += __int_as_float(t);
    return x;
}

// ---------------------------------------------------------------------------
// K1 (fused): blocks [0,64): basis MFMA fragments (bf16) + attn frags + aproj
//             blocks [64,260): init_fea = concat(feat, embed[idx]) @ T
//             blocks [260,516): per-chunk coarse dst histogram (dst>>6)
// ---------------------------------------------------------------------------
__global__ void __launch_bounds__(256) k_pre(
    const float* __restrict__ feat, const float* __restrict__ emb,
    const float* __restrict__ T, const int* __restrict__ idx,
    const float* __restrict__ weight, const float* __restrict__ A_w,
    const float* __restrict__ A_b, const float* __restrict__ attn_emb,
    const int* __restrict__ ed,
    float* __restrict__ out, unsigned short* __restrict__ init_bf,
    unsigned short* __restrict__ bfrag, unsigned short* __restrict__ afrag,
    float* __restrict__ aproj, int* __restrict__ cpb) {
    if (blockIdx.x >= 260) {                       // ---- histogram section
        __shared__ int lc[NBC];
        const int cb = blockIdx.x - 260;
        for (int i = threadIdx.x; i < NBC; i += 256) lc[i] = 0;
        __syncthreads();
        const int start = cb * CHUNK, end = min(start + CHUNK, NE);
        for (int e = start + threadIdx.x; e < end; e += 256)
            atomicAdd(&lc[ed[e] >> 6], 1);
        __syncthreads();
        for (int i = threadIdx.x; i < NBC; i += 256) cpb[cb * NBC + i] = lc[i];
        return;
    }
    if (blockIdx.x < 64) {                         // ---- fragment section
        int g = blockIdx.x * 256 + threadIdx.x;    // g < 16384
        if (g < 4 * 2 * 64 * 8) {                  // bfrag: 4096 (1024 per basis)
            int b2 = g >> 10, rest = g & 1023;
            int h = rest >> 9, l = (rest >> 3) & 63, j = rest & 7;
            int k = (l >> 4) * 8 + j, n = (l & 15) + 16 * h;
            bfrag[g] = f2bf(weight[b2 * 1024 + k * 32 + n]);
        }
        if (g < 2 * 2 * 64 * 8) {                  // afrag: 2048 (1024 per ks)
            int ks = g >> 10, rest = g & 1023;
            int nt = rest >> 9, l = (rest >> 3) & 63, j = rest & 7;
            int k = ks * 32 + (l >> 4) * 8 + j, n = (l & 15) + 16 * nt;
            afrag[g] = f2bf(A_w[k * 32 + n]);
        }
        if (g < 16 * 32) {                         // aproj: 512
            int t = g >> 5, j = g & 31;
            float acc = A_b[j];
#pragma unroll
            for (int k = 0; k < 32; k++) acc += attn_emb[t * 32 + k] * A_w[(64 + k) * 32 + j];
            aproj[g] = acc;
        }
        return;
    }
    int i = (blockIdx.x - 64) * 256 + threadIdx.x; // ---- init_fea section
    if (i >= NN) return;
    float v[32], acc[32];
#pragma unroll
    for (int o = 0; o < 32; o++) acc[o] = 0.f;
    const float4* fp = (const float4*)(feat + (size_t)i * 32);
#pragma unroll
    for (int q = 0; q < 8; q++) {
        float4 f = fp[q];
        v[4 * q] = f.x; v[4 * q + 1] = f.y; v[4 * q + 2] = f.z; v[4 * q + 3] = f.w;
    }
#pragma unroll
    for (int d = 0; d < 32; d++) {
        float xd = v[d];
#pragma unroll
        for (int o = 0; o < 32; o++) acc[o] += xd * T[d * 32 + o];
    }
    int row = idx[i];
    const float4* ep = (const float4*)(emb + (size_t)row * 32);
#pragma unroll
    for (int q = 0; q < 8; q++) {
        float4 f = ep[q];
        v[4 * q] = f.x; v[4 * q + 1] = f.y; v[4 * q + 2] = f.z; v[4 * q + 3] = f.w;
    }
#pragma unroll
    for (int d = 0; d < 32; d++) {
        float xd = v[d];
#pragma unroll
        for (int o = 0; o < 32; o++) acc[o] += xd * T[(32 + d) * 32 + o];
    }
    float4* op = (float4*)(out + (size_t)i * 64);
#pragma unroll
    for (int q = 0; q < 8; q++) {
        float4 f;
        f.x = acc[4 * q]; f.y = acc[4 * q + 1]; f.z = acc[4 * q + 2]; f.w = acc[4 * q + 3];
        op[q] = f;
    }
    unsigned int w[16];
#pragma unroll
    for (int q = 0; q < 16; q++)
        w[q] = (unsigned int)f2bf(acc[2 * q]) | ((unsigned int)f2bf(acc[2 * q + 1]) << 16);
    uint4* bp = (uint4*)(init_bf + (size_t)i * 32);
#pragma unroll
    for (int q = 0; q < 4; q++) {
        uint4 u; u.x = w[4 * q]; u.y = w[4 * q + 1]; u.z = w[4 * q + 2]; u.w = w[4 * q + 3];
        bp[q] = u;
    }
}

// ---------------------------------------------------------------------------
// K2a: per-bin scan over the 256 chunks.
// ---------------------------------------------------------------------------
__global__ void __launch_bounds__(256) k_scan1(const int* __restrict__ cpb,
                                               int* __restrict__ cpbx,
                                               int* __restrict__ tot) {
    int bin = blockIdx.x * 256 + threadIdx.x;
    if (bin >= NBC) return;
    int run = 0;
#pragma unroll 8
    for (int c = 0; c < ABLK; c++) {
        int v = cpb[c * NBC + bin];
        cpbx[c * NBC + bin] = run;
        run += v;
    }
    tot[bin] = run;
}

// ---------------------------------------------------------------------------
// K2b: single-block Hillis-Steele prefix over the 782 bucket totals -> boff.
// ---------------------------------------------------------------------------
__global__ void __launch_bounds__(1024) k_scan2(const int* __restrict__ tot,
                                                int* __restrict__ boff) {
    __shared__ int ls[1024];
    int t = threadIdx.x;
    int v = (t < NBC) ? tot[t] : 0;
    ls[t] = v;
    __syncthreads();
    for (int off = 1; off < 1024; off <<= 1) {
        int u = (t >= off) ? ls[t - off] : 0;
        __syncthreads();
        ls[t] += u;
        __syncthreads();
    }
    if (t < NBC) boff[t] = ls[t] - v;          // exclusive
    if (t == NBC - 1) boff[NBC] = ls[t];       // == NE
}

// ---------------------------------------------------------------------------
// K3: scatter edges into dst-bucket order (LDS cursors, zero global atomics).
//     One packed int per edge: src(16b) | dst&63 (6b) | type (4b).
// ---------------------------------------------------------------------------
__global__ void __launch_bounds__(1024) k_scatA(const int* __restrict__ es,
                                                const int* __restrict__ ed,
                                                const int* __restrict__ et,
                                                const int* __restrict__ cpbx,
                                                const int* __restrict__ boff,
                                                int* __restrict__ bpack) {
    __shared__ int cur[NBC];
    const int start = blockIdx.x * CHUNK, end = min(start + CHUNK, NE);
    for (int i = threadIdx.x; i < NBC; i += 1024)
        cur[i] = boff[i] + cpbx[blockIdx.x * NBC + i];
    __syncthreads();
    for (int e = start + threadIdx.x; e < end; e += 1024) {
        int s = es[e], d = ed[e], t = et[e];
        int slot = atomicAdd(&cur[d >> 6], 1);
        bpack[slot] = s | ((d & 63) << 16) | (t << 22);
    }
}

// ---------------------------------------------------------------------------
// K4: fine counting sort within each 64-node bucket (one block per bucket).
// Produces row_off (CSR by dst) and the fully dst-sorted edge arrays
// e1 = src | (type<<16), e2 = dst. LDS atomics only.
// ---------------------------------------------------------------------------
__global__ void __launch_bounds__(256) k_fine(const int* __restrict__ boff,
                                              const int* __restrict__ bpack,
                                              int* __restrict__ row_off,
                                              int* __restrict__ e1,
                                              unsigned short* __restrict__ e2) {
    __shared__ int h[BNODE], ls[BNODE], cur[BNODE];
    const int b = blockIdx.x, tid = threadIdx.x;
    const int s0 = boff[b], s1 = boff[b + 1];
    if (tid < BNODE) h[tid] = 0;
    __syncthreads();
    for (int s = s0 + tid; s < s1; s += 256)
        atomicAdd(&h[(bpack[s] >> 16) & 63], 1);
    __syncthreads();
    if (tid < BNODE) ls[tid] = h[tid];
    __syncthreads();
    for (int off = 1; off < BNODE; off <<= 1) {
        int u = (tid < BNODE && tid >= off) ? ls[tid - off] : 0;
        __syncthreads();
        if (tid < BNODE) ls[tid] += u;
        __syncthreads();
    }
    if (tid < BNODE) {
        int excl = ls[tid] - h[tid];
        int node = b * BNODE + tid;
        if (node <= NN) row_off[node] = s0 + excl;   // covers row_off[NN]=NE
        cur[tid] = s0 + excl;
    }
    __syncthreads();
    for (int s = s0 + tid; s < s1; s += 256) {
        int pk = bpack[s];
        int f = (pk >> 16) & 63;
        int p = atomicAdd(&cur[f], 1);
        e1[p] = (pk & 0xffff) | (((pk >> 22) & 15) << 16);
        e2[p] = (unsigned short)(b * BNODE + f);
    }
}

// ---------------------------------------------------------------------------
// K5: edge-tile MFMA kernel. TPW=4 dst-sorted 16-edge tiles per wave.
// R10: 2-deep gather pipeline (xa/ya for tiles t+1 AND t+2 in flight during
// tile t's compute — k_msg is HBM-gather-latency-bound at ~2.6 blocks/CU and
// needs per-wave MLP, not more instructions removed) + s_ap padded to stride
// 33 (R9's stride-32 layout was a 4-way LDS bank conflict, 750K/dispatch).
// ---------------------------------------------------------------------------
__global__ void __launch_bounds__(256) k_msg(
    const unsigned short* __restrict__ bfrag, const unsigned short* __restrict__ afrag,
    const float* __restrict__ aproj, const float* __restrict__ w_comp,
    const float* __restrict__ B_w, const float* __restrict__ B_b,
    const int* __restrict__ e1, const unsigned short* __restrict__ e2,
    const unsigned short* __restrict__ init_bf, unsigned int* __restrict__ amsg32) {
    __shared__ float s_ap[NR * 33];                // stride 33: bank = (tr+m)%32
    __shared__ float4 s_wc[NR];                    // 256 B
    const int tid = threadIdx.x;
    const int wave = tid >> 6;
    const int lane = tid & 63;
    const int m = lane & 15, quad = lane >> 4;
    const int t0 = (blockIdx.x * 4 + wave) * TPW;  // tile base, exact coverage
    // ---- stage small tables to LDS (once per block; strided loops)
    for (int i = tid; i < NR * 32; i += 256) s_ap[(i >> 5) * 33 + (i & 31)] = aproj[i];
    if (tid < NR) s_wc[tid] = ((const float4*)w_comp)[tid];
    // ---- hoisted fragments / constants (amortized over TPW tiles)
    const short8* bfp = (const short8*)bfrag;
    const short8* afp = (const short8*)afrag;
    short8 af0 = afp[0 * 64 + lane], af1 = afp[1 * 64 + lane];
    short8 af2 = afp[2 * 64 + lane], af3 = afp[3 * 64 + lane];
    short8 bf0 = bfp[0 * 64 + lane], bf1 = bfp[1 * 64 + lane];
    short8 bf2 = bfp[2 * 64 + lane], bf3 = bfp[3 * 64 + lane];
    short8 bf4 = bfp[4 * 64 + lane], bf5 = bfp[5 * 64 + lane];
    short8 bf6 = bfp[6 * 64 + lane], bf7 = bfp[7 * 64 + lane];
    const float bw0 = B_w[m], bw1 = B_w[m + 16], bb = B_b[0];
    const unsigned short* ibq = init_bf + quad * 8;
    // ---- all tile metadata upfront
    int ev[TPW]; int dv[TPW];
#pragma unroll
    for (int t = 0; t < TPW; t++) {
        ev[t] = e1[(t0 + t) * 16 + m];
        dv[t] = e2[(t0 + t) * 16 + m];
    }
    __syncthreads();                               // s_ap / s_wc ready
    // ---- gather pipeline (2-deep: tiles t+1 and t+2 in flight)
    const short8 z8 = {0, 0, 0, 0, 0, 0, 0, 0};
    short8 xa0 = *(const short8*)(ibq + (size_t)(ev[0] & 0xffff) * 32);
    short8 ya0 = *(const short8*)(ibq + (size_t)dv[0] * 32);
    short8 xa1 = *(const short8*)(ibq + (size_t)(ev[1] & 0xffff) * 32);
    short8 ya1 = *(const short8*)(ibq + (size_t)dv[1] * 32);
#pragma unroll
    for (int t = 0; t < TPW; t++) {
        short8 xa2 = z8, ya2 = z8;
        if (t + 2 < TPW) {                         // keep 2 tiles of gathers in flight
            xa2 = *(const short8*)(ibq + (size_t)(ev[t + 2] & 0xffff) * 32);
            ya2 = *(const short8*)(ibq + (size_t)dv[t + 2] * 32);
        }
        const int ti = t0 + t;
        // per-edge metadata: edges quad*4+0..3, one quad-uniform int4 load
        const int4 evq = *(const int4*)(e1 + ti * 16 + quad * 4);
        int tr[4];
        tr[0] = (evq.x >> 16) & 15; tr[1] = (evq.y >> 16) & 15;
        tr[2] = (evq.z >> 16) & 15; tr[3] = (evq.w >> 16) & 15;
        float4 wcr[4];
#pragma unroll
        for (int r = 0; r < 4; r++) wcr[r] = s_wc[tr[r]];
        floatx4 z4 = {0.f, 0.f, 0.f, 0.f};
        // attention MFMAs
        floatx4 hc0 = __builtin_amdgcn_mfma_f32_16x16x32_bf16(xa0, af0, z4, 0, 0, 0);
        hc0 = __builtin_amdgcn_mfma_f32_16x16x32_bf16(ya0, af2, hc0, 0, 0, 0);
        floatx4 hc1 = __builtin_amdgcn_mfma_f32_16x16x32_bf16(xa0, af1, z4, 0, 0, 0);
        hc1 = __builtin_amdgcn_mfma_f32_16x16x32_bf16(ya0, af3, hc1, 0, 0, 0);
        // basis message MFMAs, folded per basis
        floatx4 m0 = z4, m1 = z4;
        {
            floatx4 zb0 = __builtin_amdgcn_mfma_f32_16x16x32_bf16(xa0, bf0, z4, 0, 0, 0);
            floatx4 zb1 = __builtin_amdgcn_mfma_f32_16x16x32_bf16(xa0, bf1, z4, 0, 0, 0);
#pragma unroll
            for (int r = 0; r < 4; r++) { m0[r] += wcr[r].x * zb0[r]; m1[r] += wcr[r].x * zb1[r]; }
        }
        {
            floatx4 zb0 = __builtin_amdgcn_mfma_f32_16x16x32_bf16(xa0, bf2, z4, 0, 0, 0);
            floatx4 zb1 = __builtin_amdgcn_mfma_f32_16x16x32_bf16(xa0, bf3, z4, 0, 0, 0);
#pragma unroll
            for (int r = 0; r < 4; r++) { m0[r] += wcr[r].y * zb0[r]; m1[r] += wcr[r].y * zb1[r]; }
        }
        {
            floatx4 zb0 = __builtin_amdgcn_mfma_f32_16x16x32_bf16(xa0, bf4, z4, 0, 0, 0);
            floatx4 zb1 = __builtin_amdgcn_mfma_f32_16x16x32_bf16(xa0, bf5, z4, 0, 0, 0);
#pragma unroll
            for (int r = 0; r < 4; r++) { m0[r] += wcr[r].z * zb0[r]; m1[r] += wcr[r].z * zb1[r]; }
        }
        {
            floatx4 zb0 = __builtin_amdgcn_mfma_f32_16x16x32_bf16(xa0, bf6, z4, 0, 0, 0);
            floatx4 zb1 = __builtin_amdgcn_mfma_f32_16x16x32_bf16(xa0, bf7, z4, 0, 0, 0);
#pragma unroll
            for (int r = 0; r < 4; r++) { m0[r] += wcr[r].w * zb0[r]; m1[r] += wcr[r].w * zb1[r]; }
        }
        // attention MLP + DPP 16-lane reduce (each quad is one DPP row)
        float part[4];
#pragma unroll
        for (int r = 0; r < 4; r++) {
            float p = fmaxf(hc0[r] + s_ap[tr[r] * 33 + m], 0.f) * bw0
                    + fmaxf(hc1[r] + s_ap[tr[r] * 33 + 16 + m], 0.f) * bw1;
            part[r] = rsum16(p);
        }
#pragma unroll
        for (int r = 0; r < 4; r++) {
            const int p = ti * 16 + quad * 4 + r;  // sequential: edges dst-sorted
            float a = 1.f / (1.f + __expf(-(part[r] + bb)));
            unsigned int pk;
            asm("v_cvt_pk_bf16_f32 %0, %1, %2" : "=v"(pk) : "v"(a * m0[r]), "v"(a * m1[r]));
            amsg32[(size_t)p * 16 + m] = pk;
        }
        xa0 = xa1; ya0 = ya1; xa1 = xa2; ya1 = ya2;
    }
}

// ---------------------------------------------------------------------------
// K6: dst-major aggregation + fused self-loop GEMM + ReLU (streaming amsg).
// amsg rows are packed u32: u32[m] = bf16(col m) | bf16(col m+16)<<16.
// Thread covering cols c0..c0+7 reads u32[(c0&8)..(c0&8)+7], lo/hi half.
// ---------------------------------------------------------------------------
__global__ void __launch_bounds__(256) k_agg(
    const int* __restrict__ row_off, const unsigned int* __restrict__ amsg32,
    const float* __restrict__ S, float* __restrict__ out) {
    int tid = threadIdx.x;
    int v = blockIdx.x * 64 + (tid >> 2);
    if (v >= NN) return;
    int c0 = (tid & 3) * 8;
    const int base = c0 & 8;
    const bool hi = c0 >= 16;
    float acc[8];
#pragma unroll
    for (int j = 0; j < 8; j++) acc[j] = 0.f;
    int p0 = row_off[v], p1 = row_off[v + 1];
    for (int p = p0; p < p1; p++) {
        const uint4* rp = (const uint4*)(amsg32 + (size_t)p * 16 + base);
        uint4 u0 = rp[0], u1 = rp[1];
        unsigned int uu[8] = {u0.x, u0.y, u0.z, u0.w, u1.x, u1.y, u1.z, u1.w};
#pragma unroll
        for (int j = 0; j < 8; j++) {
            unsigned int raw = hi ? (uu[j] & 0xffff0000u) : (uu[j] << 16);
            acc[j] += __uint_as_float(raw);
        }
    }
    float x[32];
    const float4* xp = (const float4*)(out + (size_t)v * 64);
#pragma unroll
    for (int q = 0; q < 8; q++) {
        float4 f = xp[q];
        x[4 * q] = f.x; x[4 * q + 1] = f.y; x[4 * q + 2] = f.z; x[4 * q + 3] = f.w;
    }
#pragma unroll
    for (int d = 0; d < 32; d++) {
        float xd = x[d];
#pragma unroll
        for (int j = 0; j < 8; j++) acc[j] += xd * S[d * 32 + c0 + j];
    }
    float4* op = (float4*)(out + (size_t)v * 64 + 32 + c0);
#pragma unroll
    for (int q = 0; q < 2; q++) {
        float4 f;
        f.x = fmaxf(acc[4 * q], 0.f);
        f.y = fmaxf(acc[4 * q + 1], 0.f);
        f.z = fmaxf(acc[4 * q + 2], 0.f);
        f.w = fmaxf(acc[4 * q + 3], 0.f);
        op[q] = f;
    }
}

extern "C" void kernel_launch(void* const* d_in, const int* in_sizes, int n_in,
                              void* d_out, int out_size, void* d_ws, size_t ws_size,
                              hipStream_t stream) {
    const float* feat      = (const float*)d_in[0];
    const float* embed     = (const float*)d_in[1];
    const float* transform = (const float*)d_in[2];
    const float* weight    = (const float*)d_in[3];
    const float* w_comp    = (const float*)d_in[4];
    const float* self_w    = (const float*)d_in[5];
    const float* A_w       = (const float*)d_in[6];
    const float* A_b       = (const float*)d_in[7];
    const float* B_w       = (const float*)d_in[8];
    const float* B_b       = (const float*)d_in[9];
    const float* attn_emb  = (const float*)d_in[10];
    const int*   idx       = (const int*)d_in[11];
    const int*   edge_src  = (const int*)d_in[12];
    const int*   edge_dst  = (const int*)d_in[13];
    const int*   edge_type = (const int*)d_in[14];
    float* out = (float*)d_out;

    // -------- workspace layout (~61 MB) --------
    char* ws = (char*)d_ws;
    unsigned int*   amsg32  = (unsigned int*)ws;                   // NE*64 B = 51,200,000
    int*            bpack   = (int*)ws;      // aliases amsg32[0 .. NE*4B): consumed by k_fine
                                             // BEFORE k_msg overwrites the region.
    unsigned short* init_bf = (unsigned short*)(ws + (size_t)NE * 64);               // 3,200,000 B
    unsigned short* bfrag   = (unsigned short*)((char*)init_bf + 3200000);           // 8,192 B
    unsigned short* afrag   = (unsigned short*)((char*)bfrag + 8192);                // 4,096 B
    float*          aproj   = (float*)((char*)afrag + 4096);                         // 2,048 B
    int* ip      = (int*)((char*)aproj + 2048);
    int* boff    = ip;            ip += NBC + 2;        // 783 used
    int* tot     = ip;            ip += 1024;
    int* cpb     = ip;            ip += ABLK * NBC;     // 200,192
    int* cpbx    = ip;            ip += ABLK * NBC;     // 200,192
    int* row_off = ip;            ip += NN + 1;
    int* e1      = ip;            ip += NE;             // 3,200,000 B
    unsigned short* e2 = (unsigned short*)ip;           // 1,600,000 B

    k_pre<<<516, 256, 0, stream>>>(feat, embed, transform, idx, weight,
                                   A_w, A_b, attn_emb, edge_dst,
                                   out, init_bf, bfrag, afrag, aproj, cpb);
    k_scan1<<<4, 256, 0, stream>>>(cpb, cpbx, tot);
    k_scan2<<<1, 1024, 0, stream>>>(tot, boff);
    k_scatA<<<ABLK, 1024, 0, stream>>>(edge_src, edge_dst, edge_type, cpbx, boff, bpack);
    k_fine<<<NBC, 256, 0, stream>>>(boff, bpack, row_off, e1, e2);
    k_msg<<<NTILE / (4 * TPW), 256, 0, stream>>>(bfrag, afrag, aproj, w_comp, B_w, B_b,
                                                 e1, e2, init_bf, amsg32);
    k_agg<<<(NN + 63) / 64, 256, 0, stream>>>(row_off, amsg32, self_w, out);
}

// Round 12
// 207.093 us; speedup vs baseline: 1.0077x; 1.0077x over previous
//
#include <hip/hip_runtime.h>
#include <math.h>

#define NN 50000
#define NE 800000
#define NR 16
#define BNODE 64                          // nodes per dst bucket
#define NBC 782                           // ceil(50000/64) buckets
#define ABLK 256                          // chunks in count/scatter passes
#define CHUNK ((NE + ABLK - 1) / ABLK)    // 3125
#define NTILE (NE / 16)                   // 50000 exact, no tail
#define TPW 4                             // tiles per wave (50000/4/4 = 3125 blocks exact)

typedef __attribute__((ext_vector_type(8))) short short8;
typedef __attribute__((ext_vector_type(4))) float floatx4;

__device__ __forceinline__ unsigned short f2bf(float x) {
    unsigned int u = __float_as_uint(x);
    u += 0x7fffu + ((u >> 16) & 1u);
    return (unsigned short)(u >> 16);
}
__device__ __forceinline__ float bf2f(unsigned short s) {
    return __uint_as_float(((unsigned int)s) << 16);
}

// 16-lane (DPP-row) sum: every lane of each 16-lane row ends with the row total.
__device__ __forceinline__ float rsum16(float x) {
    int t;
    t = __builtin_amdgcn_update_dpp(0, __float_as_int(x), 0x128, 0xF, 0xF, true);
    x += __int_as_float(t);
    t = __builtin_amdgcn_update_dpp(0, __float_as_int(x), 0x124, 0xF, 0xF, true);
    x += __int_as_float(t);
    t = __builtin_amdgcn_update_dpp(0, __float_as_int(x), 0x122, 0xF, 0xF, true);
    x += __int_as_float(t);
    t = __builtin_amdgcn_update_dpp(0, __float_as_int(x), 0x121, 0xF, 0xF, true);
    x += __int_as_float(t);
    return x;
}

// ---------------------------------------------------------------------------
// K1 (fused): blocks [0,64): basis MFMA fragments (bf16) + attn frags + aproj
//             blocks [64,260): init_fea = concat(feat, embed[idx]) @ T
//             blocks [260,516): per-chunk coarse dst histogram (dst>>6)
// ---------------------------------------------------------------------------
__global__ void __launch_bounds__(256) k_pre(
    const float* __restrict__ feat, const float* __restrict__ emb,
    const float* __restrict__ T, const int* __restrict__ idx,
    const float* __restrict__ weight, const float* __restrict__ A_w,
    const float* __restrict__ A_b, const float* __restrict__ attn_emb,
    const int* __restrict__ ed,
    float* __restrict__ out, unsigned short* __restrict__ init_bf,
    unsigned short* __restrict__ bfrag, unsigned short* __restrict__ afrag,
    float* __restrict__ aproj, int* __restrict__ cpb) {
    if (blockIdx.x >= 260) {                       // ---- histogram section
        __shared__ int lc[NBC];
        const int cb = blockIdx.x - 260;
        for (int i = threadIdx.x; i < NBC; i += 256) lc[i] = 0;
        __syncthreads();
        const int start = cb * CHUNK, end = min(start + CHUNK, NE);
        for (int e = start + threadIdx.x; e < end; e += 256)
            atomicAdd(&lc[ed[e] >> 6], 1);
        __syncthreads();
        for (int i = threadIdx.x; i < NBC; i += 256) cpb[cb * NBC + i] = lc[i];
        return;
    }
    if (blockIdx.x < 64) {                         // ---- fragment section
        int g = blockIdx.x * 256 + threadIdx.x;    // g < 16384
        if (g < 4 * 2 * 64 * 8) {                  // bfrag: 4096 (1024 per basis)
            int b2 = g >> 10, rest = g & 1023;
            int h = rest >> 9, l = (rest >> 3) & 63, j = rest & 7;
            int k = (l >> 4) * 8 + j, n = (l & 15) + 16 * h;
            bfrag[g] = f2bf(weight[b2 * 1024 + k * 32 + n]);
        }
        if (g < 2 * 2 * 64 * 8) {                  // afrag: 2048 (1024 per ks)
            int ks = g >> 10, rest = g & 1023;
            int nt = rest >> 9, l = (rest >> 3) & 63, j = rest & 7;
            int k = ks * 32 + (l >> 4) * 8 + j, n = (l & 15) + 16 * nt;
            afrag[g] = f2bf(A_w[k * 32 + n]);
        }
        if (g < 16 * 32) {                         // aproj: 512
            int t = g >> 5, j = g & 31;
            float acc = A_b[j];
#pragma unroll
            for (int k = 0; k < 32; k++) acc += attn_emb[t * 32 + k] * A_w[(64 + k) * 32 + j];
            aproj[g] = acc;
        }
        return;
    }
    int i = (blockIdx.x - 64) * 256 + threadIdx.x; // ---- init_fea section
    if (i >= NN) return;
    float v[32], acc[32];
#pragma unroll
    for (int o = 0; o < 32; o++) acc[o] = 0.f;
    const float4* fp = (const float4*)(feat + (size_t)i * 32);
#pragma unroll
    for (int q = 0; q < 8; q++) {
        float4 f = fp[q];
        v[4 * q] = f.x; v[4 * q + 1] = f.y; v[4 * q + 2] = f.z; v[4 * q + 3] = f.w;
    }
#pragma unroll
    for (int d = 0; d < 32; d++) {
        float xd = v[d];
#pragma unroll
        for (int o = 0; o < 32; o++) acc[o] += xd * T[d * 32 + o];
    }
    int row = idx[i];
    const float4* ep = (const float4*)(emb + (size_t)row * 32);
#pragma unroll
    for (int q = 0; q < 8; q++) {
        float4 f = ep[q];
        v[4 * q] = f.x; v[4 * q + 1] = f.y; v[4 * q + 2] = f.z; v[4 * q + 3] = f.w;
    }
#pragma unroll
    for (int d = 0; d < 32; d++) {
        float xd = v[d];
#pragma unroll
        for (int o = 0; o < 32; o++) acc[o] += xd * T[(32 + d) * 32 + o];
    }
    float4* op = (float4*)(out + (size_t)i * 64);
#pragma unroll
    for (int q = 0; q < 8; q++) {
        float4 f;
        f.x = acc[4 * q]; f.y = acc[4 * q + 1]; f.z = acc[4 * q + 2]; f.w = acc[4 * q + 3];
        op[q] = f;
    }
    unsigned int w[16];
#pragma unroll
    for (int q = 0; q < 16; q++)
        w[q] = (unsigned int)f2bf(acc[2 * q]) | ((unsigned int)f2bf(acc[2 * q + 1]) << 16);
    uint4* bp = (uint4*)(init_bf + (size_t)i * 32);
#pragma unroll
    for (int q = 0; q < 4; q++) {
        uint4 u; u.x = w[4 * q]; u.y = w[4 * q + 1]; u.z = w[4 * q + 2]; u.w = w[4 * q + 3];
        bp[q] = u;
    }
}

// ---------------------------------------------------------------------------
// K2: merged scan (was scan1 + scan2). One block, 1024 threads: thread = bin
// (782 <= 1024; cpb[c*NBC+bin] is consecutive in bin -> coalesced), then an
// in-block Hillis-Steele over bucket totals -> boff. Deletes one launch and
// the tot[] global round-trip. No cooperative/grid-sync machinery.
// ---------------------------------------------------------------------------
__global__ void __launch_bounds__(1024) k_scan(const int* __restrict__ cpb,
                                               int* __restrict__ cpbx,
                                               int* __restrict__ boff) {
    __shared__ int ls[1024];
    const int bin = threadIdx.x;
    int run = 0;
    if (bin < NBC) {
#pragma unroll 8
        for (int c = 0; c < ABLK; c++) {
            int v = cpb[c * NBC + bin];
            cpbx[c * NBC + bin] = run;
            run += v;
        }
    }
    int v = (bin < NBC) ? run : 0;
    ls[bin] = v;
    __syncthreads();
    for (int off = 1; off < 1024; off <<= 1) {
        int u = (bin >= off) ? ls[bin - off] : 0;
        __syncthreads();
        ls[bin] += u;
        __syncthreads();
    }
    if (bin < NBC) boff[bin] = ls[bin] - v;        // exclusive
    if (bin == NBC - 1) boff[NBC] = ls[bin];       // == NE
}

// ---------------------------------------------------------------------------
// K3: scatter edges into dst-bucket order (LDS cursors, zero global atomics).
//     One packed int per edge: src(16b) | dst&63 (6b) | type (4b).
// ---------------------------------------------------------------------------
__global__ void __launch_bounds__(1024) k_scatA(const int* __restrict__ es,
                                                const int* __restrict__ ed,
                                                const int* __restrict__ et,
                                                const int* __restrict__ cpbx,
                                                const int* __restrict__ boff,
                                                int* __restrict__ bpack) {
    __shared__ int cur[NBC];
    const int start = blockIdx.x * CHUNK, end = min(start + CHUNK, NE);
    for (int i = threadIdx.x; i < NBC; i += 1024)
        cur[i] = boff[i] + cpbx[blockIdx.x * NBC + i];
    __syncthreads();
    for (int e = start + threadIdx.x; e < end; e += 1024) {
        int s = es[e], d = ed[e], t = et[e];
        int slot = atomicAdd(&cur[d >> 6], 1);
        bpack[slot] = s | ((d & 63) << 16) | (t << 22);
    }
}

// ---------------------------------------------------------------------------
// K4: fine counting sort within each 64-node bucket (one block per bucket).
// Produces row_off (CSR by dst) and the fully dst-sorted edge arrays
// e1 = src | (type<<16), e2 = dst. LDS atomics only.
// ---------------------------------------------------------------------------
__global__ void __launch_bounds__(256) k_fine(const int* __restrict__ boff,
                                              const int* __restrict__ bpack,
                                              int* __restrict__ row_off,
                                              int* __restrict__ e1,
                                              unsigned short* __restrict__ e2) {
    __shared__ int h[BNODE], ls[BNODE], cur[BNODE];
    const int b = blockIdx.x, tid = threadIdx.x;
    const int s0 = boff[b], s1 = boff[b + 1];
    if (tid < BNODE) h[tid] = 0;
    __syncthreads();
    for (int s = s0 + tid; s < s1; s += 256)
        atomicAdd(&h[(bpack[s] >> 16) & 63], 1);
    __syncthreads();
    if (tid < BNODE) ls[tid] = h[tid];
    __syncthreads();
    for (int off = 1; off < BNODE; off <<= 1) {
        int u = (tid < BNODE && tid >= off) ? ls[tid - off] : 0;
        __syncthreads();
        if (tid < BNODE) ls[tid] += u;
        __syncthreads();
    }
    if (tid < BNODE) {
        int excl = ls[tid] - h[tid];
        int node = b * BNODE + tid;
        if (node <= NN) row_off[node] = s0 + excl;   // covers row_off[NN]=NE
        cur[tid] = s0 + excl;
    }
    __syncthreads();
    for (int s = s0 + tid; s < s1; s += 256) {
        int pk = bpack[s];
        int f = (pk >> 16) & 63;
        int p = atomicAdd(&cur[f], 1);
        e1[p] = (pk & 0xffff) | (((pk >> 22) & 15) << 16);
        e2[p] = (unsigned short)(b * BNODE + f);
    }
}

// ---------------------------------------------------------------------------
// K5: edge-tile MFMA kernel (R9 best config: TPW=4, 1-deep pipeline, VGPR 64).
// ---------------------------------------------------------------------------
__global__ void __launch_bounds__(256) k_msg(
    const unsigned short* __restrict__ bfrag, const unsigned short* __restrict__ afrag,
    const float* __restrict__ aproj, const float* __restrict__ w_comp,
    const float* __restrict__ B_w, const float* __restrict__ B_b,
    const int* __restrict__ e1, const unsigned short* __restrict__ e2,
    const unsigned short* __restrict__ init_bf, unsigned int* __restrict__ amsg32) {
    __shared__ float s_ap[NR * 33];                // stride 33
    __shared__ float4 s_wc[NR];
    const int tid = threadIdx.x;
    const int wave = tid >> 6;
    const int lane = tid & 63;
    const int m = lane & 15, quad = lane >> 4;
    const int t0 = (blockIdx.x * 4 + wave) * TPW;  // tile base, exact coverage
    for (int i = tid; i < NR * 32; i += 256) s_ap[(i >> 5) * 33 + (i & 31)] = aproj[i];
    if (tid < NR) s_wc[tid] = ((const float4*)w_comp)[tid];
    const short8* bfp = (const short8*)bfrag;
    const short8* afp = (const short8*)afrag;
    short8 af0 = afp[0 * 64 + lane], af1 = afp[1 * 64 + lane];
    short8 af2 = afp[2 * 64 + lane], af3 = afp[3 * 64 + lane];
    short8 bf0 = bfp[0 * 64 + lane], bf1 = bfp[1 * 64 + lane];
    short8 bf2 = bfp[2 * 64 + lane], bf3 = bfp[3 * 64 + lane];
    short8 bf4 = bfp[4 * 64 + lane], bf5 = bfp[5 * 64 + lane];
    short8 bf6 = bfp[6 * 64 + lane], bf7 = bfp[7 * 64 + lane];
    const float bw0 = B_w[m], bw1 = B_w[m + 16], bb = B_b[0];
    const unsigned short* ibq = init_bf + quad * 8;
    int ev[TPW]; int dv[TPW];
#pragma unroll
    for (int t = 0; t < TPW; t++) {
        ev[t] = e1[(t0 + t) * 16 + m];
        dv[t] = e2[(t0 + t) * 16 + m];
    }
    __syncthreads();                               // s_ap / s_wc ready
    short8 xa = *(const short8*)(ibq + (size_t)(ev[0] & 0xffff) * 32);
    short8 ya = *(const short8*)(ibq + (size_t)dv[0] * 32);
    const short8 z8 = {0, 0, 0, 0, 0, 0, 0, 0};
#pragma unroll
    for (int t = 0; t < TPW; t++) {
        short8 xan = z8, yan = z8;
        if (t + 1 < TPW) {                         // prefetch next tile's rows
            xan = *(const short8*)(ibq + (size_t)(ev[t + 1] & 0xffff) * 32);
            yan = *(const short8*)(ibq + (size_t)dv[t + 1] * 32);
        }
        const int ti = t0 + t;
        const int4 evq = *(const int4*)(e1 + ti * 16 + quad * 4);
        int tr[4];
        tr[0] = (evq.x >> 16) & 15; tr[1] = (evq.y >> 16) & 15;
        tr[2] = (evq.z >> 16) & 15; tr[3] = (evq.w >> 16) & 15;
        float4 wcr[4];
#pragma unroll
        for (int r = 0; r < 4; r++) wcr[r] = s_wc[tr[r]];
        floatx4 z4 = {0.f, 0.f, 0.f, 0.f};
        floatx4 hc0 = __builtin_amdgcn_mfma_f32_16x16x32_bf16(xa, af0, z4, 0, 0, 0);
        hc0 = __builtin_amdgcn_mfma_f32_16x16x32_bf16(ya, af2, hc0, 0, 0, 0);
        floatx4 hc1 = __builtin_amdgcn_mfma_f32_16x16x32_bf16(xa, af1, z4, 0, 0, 0);
        hc1 = __builtin_amdgcn_mfma_f32_16x16x32_bf16(ya, af3, hc1, 0, 0, 0);
        floatx4 m0 = z4, m1 = z4;
        {
            floatx4 zb0 = __builtin_amdgcn_mfma_f32_16x16x32_bf16(xa, bf0, z4, 0, 0, 0);
            floatx4 zb1 = __builtin_amdgcn_mfma_f32_16x16x32_bf16(xa, bf1, z4, 0, 0, 0);
#pragma unroll
            for (int r = 0; r < 4; r++) { m0[r] += wcr[r].x * zb0[r]; m1[r] += wcr[r].x * zb1[r]; }
        }
        {
            floatx4 zb0 = __builtin_amdgcn_mfma_f32_16x16x32_bf16(xa, bf2, z4, 0, 0, 0);
            floatx4 zb1 = __builtin_amdgcn_mfma_f32_16x16x32_bf16(xa, bf3, z4, 0, 0, 0);
#pragma unroll
            for (int r = 0; r < 4; r++) { m0[r] += wcr[r].y * zb0[r]; m1[r] += wcr[r].y * zb1[r]; }
        }
        {
            floatx4 zb0 = __builtin_amdgcn_mfma_f32_16x16x32_bf16(xa, bf4, z4, 0, 0, 0);
            floatx4 zb1 = __builtin_amdgcn_mfma_f32_16x16x32_bf16(xa, bf5, z4, 0, 0, 0);
#pragma unroll
            for (int r = 0; r < 4; r++) { m0[r] += wcr[r].z * zb0[r]; m1[r] += wcr[r].z * zb1[r]; }
        }
        {
            floatx4 zb0 = __builtin_amdgcn_mfma_f32_16x16x32_bf16(xa, bf6, z4, 0, 0, 0);
            floatx4 zb1 = __builtin_amdgcn_mfma_f32_16x16x32_bf16(xa, bf7, z4, 0, 0, 0);
#pragma unroll
            for (int r = 0; r < 4; r++) { m0[r] += wcr[r].w * zb0[r]; m1[r] += wcr[r].w * zb1[r]; }
        }
        float part[4];
#pragma unroll
        for (int r = 0; r < 4; r++) {
            float p = fmaxf(hc0[r] + s_ap[tr[r] * 33 + m], 0.f) * bw0
                    + fmaxf(hc1[r] + s_ap[tr[r] * 33 + 16 + m], 0.f) * bw1;
            part[r] = rsum16(p);
        }
#pragma unroll
        for (int r = 0; r < 4; r++) {
            const int p = ti * 16 + quad * 4 + r;  // sequential: edges dst-sorted
            float a = 1.f / (1.f + __expf(-(part[r] + bb)));
            unsigned int pk;
            asm("v_cvt_pk_bf16_f32 %0, %1, %2" : "=v"(pk) : "v"(a * m0[r]), "v"(a * m1[r]));
            amsg32[(size_t)p * 16 + m] = pk;
        }
        xa = xan; ya = yan;
    }
}

// ---------------------------------------------------------------------------
// K6: dst-major aggregation + fused self-loop GEMM + ReLU (streaming amsg).
// amsg rows are packed u32: u32[m] = bf16(col m) | bf16(col m+16)<<16.
// ---------------------------------------------------------------------------
__global__ void __launch_bounds__(256) k_agg(
    const int* __restrict__ row_off, const unsigned int* __restrict__ amsg32,
    const float* __restrict__ S, float* __restrict__ out) {
    int tid = threadIdx.x;
    int v = blockIdx.x * 64 + (tid >> 2);
    if (v >= NN) return;
    int c0 = (tid & 3) * 8;
    const int base = c0 & 8;
    const bool hi = c0 >= 16;
    float acc[8];
#pragma unroll
    for (int j = 0; j < 8; j++) acc[j] = 0.f;
    int p0 = row_off[v], p1 = row_off[v + 1];
    for (int p = p0; p < p1; p++) {
        const uint4* rp = (const uint4*)(amsg32 + (size_t)p * 16 + base);
        uint4 u0 = rp[0], u1 = rp[1];
        unsigned int uu[8] = {u0.x, u0.y, u0.z, u0.w, u1.x, u1.y, u1.z, u1.w};
#pragma unroll
        for (int j = 0; j < 8; j++) {
            unsigned int raw = hi ? (uu[j] & 0xffff0000u) : (uu[j] << 16);
            acc[j] += __uint_as_float(raw);
        }
    }
    float x[32];
    const float4* xp = (const float4*)(out + (size_t)v * 64);
#pragma unroll
    for (int q = 0; q < 8; q++) {
        float4 f = xp[q];
        x[4 * q] = f.x; x[4 * q + 1] = f.y; x[4 * q + 2] = f.z; x[4 * q + 3] = f.w;
    }
#pragma unroll
    for (int d = 0; d < 32; d++) {
        float xd = x[d];
#pragma unroll
        for (int j = 0; j < 8; j++) acc[j] += xd * S[d * 32 + c0 + j];
    }
    float4* op = (float4*)(out + (size_t)v * 64 + 32 + c0);
#pragma unroll
    for (int q = 0; q < 2; q++) {
        float4 f;
        f.x = fmaxf(acc[4 * q], 0.f);
        f.y = fmaxf(acc[4 * q + 1], 0.f);
        f.z = fmaxf(acc[4 * q + 2], 0.f);
        f.w = fmaxf(acc[4 * q + 3], 0.f);
        op[q] = f;
    }
}

extern "C" void kernel_launch(void* const* d_in, const int* in_sizes, int n_in,
                              void* d_out, int out_size, void* d_ws, size_t ws_size,
                              hipStream_t stream) {
    const float* feat      = (const float*)d_in[0];
    const float* embed     = (const float*)d_in[1];
    const float* transform = (const float*)d_in[2];
    const float* weight    = (const float*)d_in[3];
    const float* w_comp    = (const float*)d_in[4];
    const float* self_w    = (const float*)d_in[5];
    const float* A_w       = (const float*)d_in[6];
    const float* A_b       = (const float*)d_in[7];
    const float* B_w       = (const float*)d_in[8];
    const float* B_b       = (const float*)d_in[9];
    const float* attn_emb  = (const float*)d_in[10];
    const int*   idx       = (const int*)d_in[11];
    const int*   edge_src  = (const int*)d_in[12];
    const int*   edge_dst  = (const int*)d_in[13];
    const int*   edge_type = (const int*)d_in[14];
    float* out = (float*)d_out;

    // -------- workspace layout (~61 MB) --------
    char* ws = (char*)d_ws;
    unsigned int*   amsg32  = (unsigned int*)ws;                   // NE*64 B = 51,200,000
    int*            bpack   = (int*)ws;      // aliases amsg32[0 .. NE*4B): consumed by k_fine
                                             // BEFORE k_msg overwrites the region.
    unsigned short* init_bf = (unsigned short*)(ws + (size_t)NE * 64);               // 3,200,000 B
    unsigned short* bfrag   = (unsigned short*)((char*)init_bf + 3200000);           // 8,192 B
    unsigned short* afrag   = (unsigned short*)((char*)bfrag + 8192);                // 4,096 B
    float*          aproj   = (float*)((char*)afrag + 4096);                         // 2,048 B
    int* ip      = (int*)((char*)aproj + 2048);
    int* boff    = ip;            ip += NBC + 2;        // 783 used
    int* cpb     = ip;            ip += ABLK * NBC;     // 200,192
    int* cpbx    = ip;            ip += ABLK * NBC;     // 200,192
    int* row_off = ip;            ip += NN + 1;
    int* e1      = ip;            ip += NE;             // 3,200,000 B
    unsigned short* e2 = (unsigned short*)ip;           // 1,600,000 B

    k_pre<<<516, 256, 0, stream>>>(feat, embed, transform, idx, weight,
                                   A_w, A_b, attn_emb, edge_dst,
                                   out, init_bf, bfrag, afrag, aproj, cpb);
    k_scan<<<1, 1024, 0, stream>>>(cpb, cpbx, boff);
    k_scatA<<<ABLK, 1024, 0, stream>>>(edge_src, edge_dst, edge_type, cpbx, boff, bpack);
    k_fine<<<NBC, 256, 0, stream>>>(boff, bpack, row_off, e1, e2);
    k_msg<<<NTILE / (4 * TPW), 256, 0, stream>>>(bfrag, afrag, aproj, w_comp, B_w, B_b,
                                                 e1, e2, init_bf, amsg32);
    k_agg<<<(NN + 63) / 64, 256, 0, stream>>>(row_off, amsg32, self_w, out);
}

// Round 13
// 198.029 us; speedup vs baseline: 1.0539x; 1.0458x over previous
//
#include <hip/hip_runtime.h>
#include <math.h>

#define NN 50000
#define NE 800000
#define NR 16
#define BNODE 64                          // nodes per dst bucket
#define NBC 782                           // ceil(50000/64) buckets
#define ABLK 256                          // chunks in count/scatter passes
#define CHUNK ((NE + ABLK - 1) / ABLK)    // 3125
#define NTILE (NE / 16)                   // 50000 exact, no tail
#define TPW 4                             // tiles per wave (50000/4/4 = 3125 blocks exact)

typedef __attribute__((ext_vector_type(8))) short short8;
typedef __attribute__((ext_vector_type(4))) float floatx4;

__device__ __forceinline__ unsigned short f2bf(float x) {
    unsigned int u = __float_as_uint(x);
    u += 0x7fffu + ((u >> 16) & 1u);
    return (unsigned short)(u >> 16);
}
__device__ __forceinline__ float bf2f(unsigned short s) {
    return __uint_as_float(((unsigned int)s) << 16);
}

// 16-lane (DPP-row) sum: every lane of each 16-lane row ends with the row total.
__device__ __forceinline__ float rsum16(float x) {
    int t;
    t = __builtin_amdgcn_update_dpp(0, __float_as_int(x), 0x128, 0xF, 0xF, true);
    x += __int_as_float(t);
    t = __builtin_amdgcn_update_dpp(0, __float_as_int(x), 0x124, 0xF, 0xF, true);
    x += __int_as_float(t);
    t = __builtin_amdgcn_update_dpp(0, __float_as_int(x), 0x122, 0xF, 0xF, true);
    x += __int_as_float(t);
    t = __builtin_amdgcn_update_dpp(0, __float_as_int(x), 0x121, 0xF, 0xF, true);
    x += __int_as_float(t);
    return x;
}

// ---------------------------------------------------------------------------
// K1 (fused): blocks [0,64): basis MFMA fragments (bf16) + attn frags + aproj
//             blocks [64,260): init_fea = concat(feat, embed[idx]) @ T
//             blocks [260,516): per-chunk coarse dst histogram (dst>>6)
// ---------------------------------------------------------------------------
__global__ void __launch_bounds__(256) k_pre(
    const float* __restrict__ feat, const float* __restrict__ emb,
    const float* __restrict__ T, const int* __restrict__ idx,
    const float* __restrict__ weight, const float* __restrict__ A_w,
    const float* __restrict__ A_b, const float* __restrict__ attn_emb,
    const int* __restrict__ ed,
    float* __restrict__ out, unsigned short* __restrict__ init_bf,
    unsigned short* __restrict__ bfrag, unsigned short* __restrict__ afrag,
    float* __restrict__ aproj, int* __restrict__ cpb) {
    if (blockIdx.x >= 260) {                       // ---- histogram section
        __shared__ int lc[NBC];
        const int cb = blockIdx.x - 260;
        for (int i = threadIdx.x; i < NBC; i += 256) lc[i] = 0;
        __syncthreads();
        const int start = cb * CHUNK, end = min(start + CHUNK, NE);
        for (int e = start + threadIdx.x; e < end; e += 256)
            atomicAdd(&lc[ed[e] >> 6], 1);
        __syncthreads();
        for (int i = threadIdx.x; i < NBC; i += 256) cpb[cb * NBC + i] = lc[i];
        return;
    }
    if (blockIdx.x < 64) {                         // ---- fragment section
        int g = blockIdx.x * 256 + threadIdx.x;    // g < 16384
        if (g < 4 * 2 * 64 * 8) {                  // bfrag: 4096 (1024 per basis)
            int b2 = g >> 10, rest = g & 1023;
            int h = rest >> 9, l = (rest >> 3) & 63, j = rest & 7;
            int k = (l >> 4) * 8 + j, n = (l & 15) + 16 * h;
            bfrag[g] = f2bf(weight[b2 * 1024 + k * 32 + n]);
        }
        if (g < 2 * 2 * 64 * 8) {                  // afrag: 2048 (1024 per ks)
            int ks = g >> 10, rest = g & 1023;
            int nt = rest >> 9, l = (rest >> 3) & 63, j = rest & 7;
            int k = ks * 32 + (l >> 4) * 8 + j, n = (l & 15) + 16 * nt;
            afrag[g] = f2bf(A_w[k * 32 + n]);
        }
        if (g < 16 * 32) {                         // aproj: 512
            int t = g >> 5, j = g & 31;
            float acc = A_b[j];
#pragma unroll
            for (int k = 0; k < 32; k++) acc += attn_emb[t * 32 + k] * A_w[(64 + k) * 32 + j];
            aproj[g] = acc;
        }
        return;
    }
    int i = (blockIdx.x - 64) * 256 + threadIdx.x; // ---- init_fea section
    if (i >= NN) return;
    float v[32], acc[32];
#pragma unroll
    for (int o = 0; o < 32; o++) acc[o] = 0.f;
    const float4* fp = (const float4*)(feat + (size_t)i * 32);
#pragma unroll
    for (int q = 0; q < 8; q++) {
        float4 f = fp[q];
        v[4 * q] = f.x; v[4 * q + 1] = f.y; v[4 * q + 2] = f.z; v[4 * q + 3] = f.w;
    }
#pragma unroll
    for (int d = 0; d < 32; d++) {
        float xd = v[d];
#pragma unroll
        for (int o = 0; o < 32; o++) acc[o] += xd * T[d * 32 + o];
    }
    int row = idx[i];
    const float4* ep = (const float4*)(emb + (size_t)row * 32);
#pragma unroll
    for (int q = 0; q < 8; q++) {
        float4 f = ep[q];
        v[4 * q] = f.x; v[4 * q + 1] = f.y; v[4 * q + 2] = f.z; v[4 * q + 3] = f.w;
    }
#pragma unroll
    for (int d = 0; d < 32; d++) {
        float xd = v[d];
#pragma unroll
        for (int o = 0; o < 32; o++) acc[o] += xd * T[(32 + d) * 32 + o];
    }
    float4* op = (float4*)(out + (size_t)i * 64);
#pragma unroll
    for (int q = 0; q < 8; q++) {
        float4 f;
        f.x = acc[4 * q]; f.y = acc[4 * q + 1]; f.z = acc[4 * q + 2]; f.w = acc[4 * q + 3];
        op[q] = f;
    }
    unsigned int w[16];
#pragma unroll
    for (int q = 0; q < 16; q++)
        w[q] = (unsigned int)f2bf(acc[2 * q]) | ((unsigned int)f2bf(acc[2 * q + 1]) << 16);
    uint4* bp = (uint4*)(init_bf + (size_t)i * 32);
#pragma unroll
    for (int q = 0; q < 4; q++) {
        uint4 u; u.x = w[4 * q]; u.y = w[4 * q + 1]; u.z = w[4 * q + 2]; u.w = w[4 * q + 3];
        bp[q] = u;
    }
}

// ---------------------------------------------------------------------------
// K2a: per-bin scan over the 256 chunks (bins parallel across 4 blocks/CUs —
// R12's single-block merge put all 800 KB of scan loads through one CU and
// measured +10.7 us vs this split form; reverting to isolate).
// ---------------------------------------------------------------------------
__global__ void __launch_bounds__(256) k_scan1(const int* __restrict__ cpb,
                                               int* __restrict__ cpbx,
                                               int* __restrict__ tot) {
    int bin = blockIdx.x * 256 + threadIdx.x;
    if (bin >= NBC) return;
    int run = 0;
#pragma unroll 8
    for (int c = 0; c < ABLK; c++) {
        int v = cpb[c * NBC + bin];
        cpbx[c * NBC + bin] = run;
        run += v;
    }
    tot[bin] = run;
}

// ---------------------------------------------------------------------------
// K2b: single-block Hillis-Steele prefix over the 782 bucket totals -> boff.
// ---------------------------------------------------------------------------
__global__ void __launch_bounds__(1024) k_scan2(const int* __restrict__ tot,
                                                int* __restrict__ boff) {
    __shared__ int ls[1024];
    int t = threadIdx.x;
    int v = (t < NBC) ? tot[t] : 0;
    ls[t] = v;
    __syncthreads();
    for (int off = 1; off < 1024; off <<= 1) {
        int u = (t >= off) ? ls[t - off] : 0;
        __syncthreads();
        ls[t] += u;
        __syncthreads();
    }
    if (t < NBC) boff[t] = ls[t] - v;          // exclusive
    if (t == NBC - 1) boff[NBC] = ls[t];       // == NE
}

// ---------------------------------------------------------------------------
// K3: scatter edges into dst-bucket order (LDS cursors, zero global atomics).
//     One packed int per edge: src(16b) | dst&63 (6b) | type (4b).
// ---------------------------------------------------------------------------
__global__ void __launch_bounds__(1024) k_scatA(const int* __restrict__ es,
                                                const int* __restrict__ ed,
                                                const int* __restrict__ et,
                                                const int* __restrict__ cpbx,
                                                const int* __restrict__ boff,
                                                int* __restrict__ bpack) {
    __shared__ int cur[NBC];
    const int start = blockIdx.x * CHUNK, end = min(start + CHUNK, NE);
    for (int i = threadIdx.x; i < NBC; i += 1024)
        cur[i] = boff[i] + cpbx[blockIdx.x * NBC + i];
    __syncthreads();
    for (int e = start + threadIdx.x; e < end; e += 1024) {
        int s = es[e], d = ed[e], t = et[e];
        int slot = atomicAdd(&cur[d >> 6], 1);
        bpack[slot] = s | ((d & 63) << 16) | (t << 22);
    }
}

// ---------------------------------------------------------------------------
// K4: fine counting sort within each 64-node bucket (one block per bucket).
// Produces row_off (CSR by dst) and the fully dst-sorted edge arrays
// e1 = src | (type<<16), e2 = dst. LDS atomics only.
// ---------------------------------------------------------------------------
__global__ void __launch_bounds__(256) k_fine(const int* __restrict__ boff,
                                              const int* __restrict__ bpack,
                                              int* __restrict__ row_off,
                                              int* __restrict__ e1,
                                              unsigned short* __restrict__ e2) {
    __shared__ int h[BNODE], ls[BNODE], cur[BNODE];
    const int b = blockIdx.x, tid = threadIdx.x;
    const int s0 = boff[b], s1 = boff[b + 1];
    if (tid < BNODE) h[tid] = 0;
    __syncthreads();
    for (int s = s0 + tid; s < s1; s += 256)
        atomicAdd(&h[(bpack[s] >> 16) & 63], 1);
    __syncthreads();
    if (tid < BNODE) ls[tid] = h[tid];
    __syncthreads();
    for (int off = 1; off < BNODE; off <<= 1) {
        int u = (tid < BNODE && tid >= off) ? ls[tid - off] : 0;
        __syncthreads();
        if (tid < BNODE) ls[tid] += u;
        __syncthreads();
    }
    if (tid < BNODE) {
        int excl = ls[tid] - h[tid];
        int node = b * BNODE + tid;
        if (node <= NN) row_off[node] = s0 + excl;   // covers row_off[NN]=NE
        cur[tid] = s0 + excl;
    }
    __syncthreads();
    for (int s = s0 + tid; s < s1; s += 256) {
        int pk = bpack[s];
        int f = (pk >> 16) & 63;
        int p = atomicAdd(&cur[f], 1);
        e1[p] = (pk & 0xffff) | (((pk >> 22) & 15) << 16);
        e2[p] = (unsigned short)(b * BNODE + f);
    }
}

// ---------------------------------------------------------------------------
// K5: edge-tile MFMA kernel (best config: TPW=4, 1-deep pipeline, VGPR 64,
// DPP reduce, LDS-staged tables, packed cvt_pk stores). Identical to R12.
// ---------------------------------------------------------------------------
__global__ void __launch_bounds__(256) k_msg(
    const unsigned short* __restrict__ bfrag, const unsigned short* __restrict__ afrag,
    const float* __restrict__ aproj, const float* __restrict__ w_comp,
    const float* __restrict__ B_w, const float* __restrict__ B_b,
    const int* __restrict__ e1, const unsigned short* __restrict__ e2,
    const unsigned short* __restrict__ init_bf, unsigned int* __restrict__ amsg32) {
    __shared__ float s_ap[NR * 33];                // stride 33
    __shared__ float4 s_wc[NR];
    const int tid = threadIdx.x;
    const int wave = tid >> 6;
    const int lane = tid & 63;
    const int m = lane & 15, quad = lane >> 4;
    const int t0 = (blockIdx.x * 4 + wave) * TPW;  // tile base, exact coverage
    for (int i = tid; i < NR * 32; i += 256) s_ap[(i >> 5) * 33 + (i & 31)] = aproj[i];
    if (tid < NR) s_wc[tid] = ((const float4*)w_comp)[tid];
    const short8* bfp = (const short8*)bfrag;
    const short8* afp = (const short8*)afrag;
    short8 af0 = afp[0 * 64 + lane], af1 = afp[1 * 64 + lane];
    short8 af2 = afp[2 * 64 + lane], af3 = afp[3 * 64 + lane];
    short8 bf0 = bfp[0 * 64 + lane], bf1 = bfp[1 * 64 + lane];
    short8 bf2 = bfp[2 * 64 + lane], bf3 = bfp[3 * 64 + lane];
    short8 bf4 = bfp[4 * 64 + lane], bf5 = bfp[5 * 64 + lane];
    short8 bf6 = bfp[6 * 64 + lane], bf7 = bfp[7 * 64 + lane];
    const float bw0 = B_w[m], bw1 = B_w[m + 16], bb = B_b[0];
    const unsigned short* ibq = init_bf + quad * 8;
    int ev[TPW]; int dv[TPW];
#pragma unroll
    for (int t = 0; t < TPW; t++) {
        ev[t] = e1[(t0 + t) * 16 + m];
        dv[t] = e2[(t0 + t) * 16 + m];
    }
    __syncthreads();                               // s_ap / s_wc ready
    short8 xa = *(const short8*)(ibq + (size_t)(ev[0] & 0xffff) * 32);
    short8 ya = *(const short8*)(ibq + (size_t)dv[0] * 32);
    const short8 z8 = {0, 0, 0, 0, 0, 0, 0, 0};
#pragma unroll
    for (int t = 0; t < TPW; t++) {
        short8 xan = z8, yan = z8;
        if (t + 1 < TPW) {                         // prefetch next tile's rows
            xan = *(const short8*)(ibq + (size_t)(ev[t + 1] & 0xffff) * 32);
            yan = *(const short8*)(ibq + (size_t)dv[t + 1] * 32);
        }
        const int ti = t0 + t;
        const int4 evq = *(const int4*)(e1 + ti * 16 + quad * 4);
        int tr[4];
        tr[0] = (evq.x >> 16) & 15; tr[1] = (evq.y >> 16) & 15;
        tr[2] = (evq.z >> 16) & 15; tr[3] = (evq.w >> 16) & 15;
        float4 wcr[4];
#pragma unroll
        for (int r = 0; r < 4; r++) wcr[r] = s_wc[tr[r]];
        floatx4 z4 = {0.f, 0.f, 0.f, 0.f};
        floatx4 hc0 = __builtin_amdgcn_mfma_f32_16x16x32_bf16(xa, af0, z4, 0, 0, 0);
        hc0 = __builtin_amdgcn_mfma_f32_16x16x32_bf16(ya, af2, hc0, 0, 0, 0);
        floatx4 hc1 = __builtin_amdgcn_mfma_f32_16x16x32_bf16(xa, af1, z4, 0, 0, 0);
        hc1 = __builtin_amdgcn_mfma_f32_16x16x32_bf16(ya, af3, hc1, 0, 0, 0);
        floatx4 m0 = z4, m1 = z4;
        {
            floatx4 zb0 = __builtin_amdgcn_mfma_f32_16x16x32_bf16(xa, bf0, z4, 0, 0, 0);
            floatx4 zb1 = __builtin_amdgcn_mfma_f32_16x16x32_bf16(xa, bf1, z4, 0, 0, 0);
#pragma unroll
            for (int r = 0; r < 4; r++) { m0[r] += wcr[r].x * zb0[r]; m1[r] += wcr[r].x * zb1[r]; }
        }
        {
            floatx4 zb0 = __builtin_amdgcn_mfma_f32_16x16x32_bf16(xa, bf2, z4, 0, 0, 0);
            floatx4 zb1 = __builtin_amdgcn_mfma_f32_16x16x32_bf16(xa, bf3, z4, 0, 0, 0);
#pragma unroll
            for (int r = 0; r < 4; r++) { m0[r] += wcr[r].y * zb0[r]; m1[r] += wcr[r].y * zb1[r]; }
        }
        {
            floatx4 zb0 = __builtin_amdgcn_mfma_f32_16x16x32_bf16(xa, bf4, z4, 0, 0, 0);
            floatx4 zb1 = __builtin_amdgcn_mfma_f32_16x16x32_bf16(xa, bf5, z4, 0, 0, 0);
#pragma unroll
            for (int r = 0; r < 4; r++) { m0[r] += wcr[r].z * zb0[r]; m1[r] += wcr[r].z * zb1[r]; }
        }
        {
            floatx4 zb0 = __builtin_amdgcn_mfma_f32_16x16x32_bf16(xa, bf6, z4, 0, 0, 0);
            floatx4 zb1 = __builtin_amdgcn_mfma_f32_16x16x32_bf16(xa, bf7, z4, 0, 0, 0);
#pragma unroll
            for (int r = 0; r < 4; r++) { m0[r] += wcr[r].w * zb0[r]; m1[r] += wcr[r].w * zb1[r]; }
        }
        float part[4];
#pragma unroll
        for (int r = 0; r < 4; r++) {
            float p = fmaxf(hc0[r] + s_ap[tr[r] * 33 + m], 0.f) * bw0
                    + fmaxf(hc1[r] + s_ap[tr[r] * 33 + 16 + m], 0.f) * bw1;
            part[r] = rsum16(p);
        }
#pragma unroll
        for (int r = 0; r < 4; r++) {
            const int p = ti * 16 + quad * 4 + r;  // sequential: edges dst-sorted
            float a = 1.f / (1.f + __expf(-(part[r] + bb)));
            unsigned int pk;
            asm("v_cvt_pk_bf16_f32 %0, %1, %2" : "=v"(pk) : "v"(a * m0[r]), "v"(a * m1[r]));
            amsg32[(size_t)p * 16 + m] = pk;
        }
        xa = xan; ya = yan;
    }
}

// ---------------------------------------------------------------------------
// K6: dst-major aggregation + fused self-loop GEMM + ReLU (streaming amsg).
// amsg rows are packed u32: u32[m] = bf16(col m) | bf16(col m+16)<<16.
// ---------------------------------------------------------------------------
__global__ void __launch_bounds__(256) k_agg(
    const int* __restrict__ row_off, const unsigned int* __restrict__ amsg32,
    const float* __restrict__ S, float* __restrict__ out) {
    int tid = threadIdx.x;
    int v = blockIdx.x * 64 + (tid >> 2);
    if (v >= NN) return;
    int c0 = (tid & 3) * 8;
    const int base = c0 & 8;
    const bool hi = c0 >= 16;
    float acc[8];
#pragma unroll
    for (int j = 0; j < 8; j++) acc[j] = 0.f;
    int p0 = row_off[v], p1 = row_off[v + 1];
    for (int p = p0; p < p1; p++) {
        const uint4* rp = (const uint4*)(amsg32 + (size_t)p * 16 + base);
        uint4 u0 = rp[0], u1 = rp[1];
        unsigned int uu[8] = {u0.x, u0.y, u0.z, u0.w, u1.x, u1.y, u1.z, u1.w};
#pragma unroll
        for (int j = 0; j < 8; j++) {
            unsigned int raw = hi ? (uu[j] & 0xffff0000u) : (uu[j] << 16);
            acc[j] += __uint_as_float(raw);
        }
    }
    float x[32];
    const float4* xp = (const float4*)(out + (size_t)v * 64);
#pragma unroll
    for (int q = 0; q < 8; q++) {
        float4 f = xp[q];
        x[4 * q] = f.x; x[4 * q + 1] = f.y; x[4 * q + 2] = f.z; x[4 * q + 3] = f.w;
    }
#pragma unroll
    for (int d = 0; d < 32; d++) {
        float xd = x[d];
#pragma unroll
        for (int j = 0; j < 8; j++) acc[j] += xd * S[d * 32 + c0 + j];
    }
    float4* op = (float4*)(out + (size_t)v * 64 + 32 + c0);
#pragma unroll
    for (int q = 0; q < 2; q++) {
        float4 f;
        f.x = fmaxf(acc[4 * q], 0.f);
        f.y = fmaxf(acc[4 * q + 1], 0.f);
        f.z = fmaxf(acc[4 * q + 2], 0.f);
        f.w = fmaxf(acc[4 * q + 3], 0.f);
        op[q] = f;
    }
}

extern "C" void kernel_launch(void* const* d_in, const int* in_sizes, int n_in,
                              void* d_out, int out_size, void* d_ws, size_t ws_size,
                              hipStream_t stream) {
    const float* feat      = (const float*)d_in[0];
    const float* embed     = (const float*)d_in[1];
    const float* transform = (const float*)d_in[2];
    const float* weight    = (const float*)d_in[3];
    const float* w_comp    = (const float*)d_in[4];
    const float* self_w    = (const float*)d_in[5];
    const float* A_w       = (const float*)d_in[6];
    const float* A_b       = (const float*)d_in[7];
    const float* B_w       = (const float*)d_in[8];
    const float* B_b       = (const float*)d_in[9];
    const float* attn_emb  = (const float*)d_in[10];
    const int*   idx       = (const int*)d_in[11];
    const int*   edge_src  = (const int*)d_in[12];
    const int*   edge_dst  = (const int*)d_in[13];
    const int*   edge_type = (const int*)d_in[14];
    float* out = (float*)d_out;

    // -------- workspace layout (~61 MB) --------
    char* ws = (char*)d_ws;
    unsigned int*   amsg32  = (unsigned int*)ws;                   // NE*64 B = 51,200,000
    int*            bpack   = (int*)ws;      // aliases amsg32[0 .. NE*4B): consumed by k_fine
                                             // BEFORE k_msg overwrites the region.
    unsigned short* init_bf = (unsigned short*)(ws + (size_t)NE * 64);               // 3,200,000 B
    unsigned short* bfrag   = (unsigned short*)((char*)init_bf + 3200000);           // 8,192 B
    unsigned short* afrag   = (unsigned short*)((char*)bfrag + 8192);                // 4,096 B
    float*          aproj   = (float*)((char*)afrag + 4096);                         // 2,048 B
    int* ip      = (int*)((char*)aproj + 2048);
    int* boff    = ip;            ip += NBC + 2;        // 783 used
    int* tot     = ip;            ip += 1024;
    int* cpb     = ip;            ip += ABLK * NBC;     // 200,192
    int* cpbx    = ip;            ip += ABLK * NBC;     // 200,192
    int* row_off = ip;            ip += NN + 1;
    int* e1      = ip;            ip += NE;             // 3,200,000 B
    unsigned short* e2 = (unsigned short*)ip;           // 1,600,000 B

    k_pre<<<516, 256, 0, stream>>>(feat, embed, transform, idx, weight,
                                   A_w, A_b, attn_emb, edge_dst,
                                   out, init_bf, bfrag, afrag, aproj, cpb);
    k_scan1<<<4, 256, 0, stream>>>(cpb, cpbx, tot);
    k_scan2<<<1, 1024, 0, stream>>>(tot, boff);
    k_scatA<<<ABLK, 1024, 0, stream>>>(edge_src, edge_dst, edge_type, cpbx, boff, bpack);
    k_fine<<<NBC, 256, 0, stream>>>(boff, bpack, row_off, e1, e2);
    k_msg<<<NTILE / (4 * TPW), 256, 0, stream>>>(bfrag, afrag, aproj, w_comp, B_w, B_b,
                                                 e1, e2, init_bf, amsg32);
    k_agg<<<(NN + 63) / 64, 256, 0, stream>>>(row_off, amsg32, self_w, out);
}